// Round 5
// baseline (1092.373 us; speedup 1.0000x reference)
//
#include <hip/hip_runtime.h>
#include <math.h>

#define N_ROWS 65536
#define CB 1024
#define SPLITS 4
#define JS (CB / SPLITS)   // 256 codebook entries per split

typedef float v4f __attribute__((ext_vector_type(4)));

// ---------------------------------------------------------------------------
// Exact emulation of numpy's pairwise_sum for n=64 fp32 (AVX-512 path):
//   r0..r3 = 16-lane vector loads; sum = (r0+r1)+(r2+r3);
//   then _mm512_reduce_add_ps tree: fold at lane distance 8, 4, 2, 1.
// fp contract OFF so the squares are not fused into the adds.
// ---------------------------------------------------------------------------
__device__ __forceinline__ float tree_sum64_sq(const float* x) {
#pragma clang fp contract(off)
    float sq[64];
#pragma unroll
    for (int i = 0; i < 64; ++i) sq[i] = x[i] * x[i];
    float s[16];
#pragma unroll
    for (int l = 0; l < 16; ++l) s[l] = (sq[l] + sq[l + 16]) + (sq[l + 32] + sq[l + 48]);
    float t[8];
#pragma unroll
    for (int l = 0; l < 8; ++l) t[l] = s[l] + s[l + 8];
    float u[4];
#pragma unroll
    for (int l = 0; l < 4; ++l) u[l] = t[l] + t[l + 4];
    float v0 = u[0] + u[2];
    float v1 = u[1] + u[3];
    return v0 + v1;
}

// sorted-triple insert, strict < (ties keep earlier-inserted = lower index,
// matching jax.lax.top_k stable tie-breaking when fed in ascending index order)
__device__ __forceinline__ void top3_insert(float d, int j,
                                            float& v0, float& v1, float& v2,
                                            int& i0, int& i1, int& i2) {
    bool b0 = d < v0, b1 = d < v1, b2 = d < v2;
    v2 = b1 ? v1 : (b2 ? d : v2);
    i2 = b1 ? i1 : (b2 ? j : i2);
    v1 = b0 ? v0 : (b1 ? d : v1);
    i1 = b0 ? i0 : (b1 ? j : i1);
    v0 = b0 ? d : v0;
    i0 = b0 ? j : i0;
}

// ---------------------------------------------------------------------------
// B[j] = np.sum(emb[j]**2) (exact tree emulation) + zero hist/lossAcc.
// ---------------------------------------------------------------------------
__global__ __launch_bounds__(256) void prep_kernel(const float* __restrict__ emb,
                                                   float* __restrict__ B,
                                                   int* __restrict__ hist,
                                                   float* __restrict__ lossAcc) {
    int j = blockIdx.x * 256 + threadIdx.x;
    if (j >= CB) return;
    float e[64];
    const float4* e4 = (const float4*)(emb + (size_t)j * 64);
#pragma unroll
    for (int k = 0; k < 16; ++k) {
        float4 v = e4[k];
        e[4 * k] = v.x; e[4 * k + 1] = v.y; e[4 * k + 2] = v.z; e[4 * k + 3] = v.w;
    }
    B[j] = tree_sum64_sq(e);
    hist[j] = 0;
    if (j == 0) *lossAcc = 0.0f;
}

// ---------------------------------------------------------------------------
// Score + merge + epilogue + one-hot ONES.
//
// Key decisions (each backed by a measured round):
//  * `split` through readfirstlane -> emb/B loads provably uniform -> scalar
//    s_load path (losing this was 4x, round 1).
//  * The 805 MB one-hot ZERO fill is NOT done here. Rounds 2/3/4 proved our
//    kernel-issued bulk store stream caps at ~2.6 TB/s regardless of
//    NT/plain/serial/interleaved (and R1 showed NT 16B stores amplify
//    WRITE_SIZE ~4.5x). The runtime's fillBufferAligned writes this same
//    buffer at 6.27 TB/s, so the zero fill is delegated to hipMemsetAsync
//    (stream-ordered BEFORE this kernel). Here we only scatter the <=192
//    "one" positions per block after the merge.
//  * out0 stores are plain (not NT) float4 — avoids the NT amplification.
// Scoring FP order, merge tie semantics, epilogue: bit-identical to R2/R3/R4.
// ---------------------------------------------------------------------------
__global__ __launch_bounds__(256) void score_kernel(const float* __restrict__ z,
                                                    const float* __restrict__ emb,
                                                    const float* __restrict__ B,
                                                    float* __restrict__ out0,
                                                    float* __restrict__ out3f,
                                                    float* __restrict__ out4,
                                                    int* __restrict__ hist,
                                                    float* __restrict__ lossAcc) {
    __shared__ float sD[SPLITS][64][3];
    __shared__ int   sI[SPLITS][64][3];

    int t = threadIdx.x;
    int r = t & 63;
    int split = __builtin_amdgcn_readfirstlane(t >> 6);   // uniform -> scalar loads
    int row = blockIdx.x * 64 + r;

    float zr[64];
    const float4* z4 = (const float4*)(z + (size_t)row * 64);
#pragma unroll
    for (int k = 0; k < 16; ++k) {
        float4 v = z4[k];
        zr[4 * k] = v.x; zr[4 * k + 1] = v.y; zr[4 * k + 2] = v.z; zr[4 * k + 3] = v.w;
    }
    float A = tree_sum64_sq(zr);

    float v0 = 3.402823466e38f, v1 = 3.402823466e38f, v2 = 3.402823466e38f;
    int i0 = 0, i1 = 0, i2 = 0;
    int jbase = split * JS;

#pragma unroll 2
    for (int jj = 0; jj < JS; ++jj) {
        int j = jbase + jj;                   // uniform (split is readfirstlane'd)
        const float4* e4 = (const float4*)(emb + (size_t)j * 64);
        float Bj = B[j];                      // uniform -> scalar load
        float acc = 0.0f;
#pragma unroll
        for (int k = 0; k < 16; ++k) {
            float4 e = e4[k];                 // uniform -> scalar loads
            acc = fmaf(zr[4 * k],     e.x, acc);
            acc = fmaf(zr[4 * k + 1], e.y, acc);
            acc = fmaf(zr[4 * k + 2], e.z, acc);
            acc = fmaf(zr[4 * k + 3], e.w, acc);
        }
        float d = (A + Bj) - 2.0f * acc;      // fma-contraction bit-identical
        top3_insert(d, j, v0, v1, v2, i0, i1, i2);
    }

    sD[split][r][0] = v0; sD[split][r][1] = v1; sD[split][r][2] = v2;
    sI[split][r][0] = i0; sI[split][r][1] = i1; sI[split][r][2] = i2;
    __syncthreads();

    if (t < 64) {                             // wave 0: zr holds row's z (split 0)
        float m0 = 3.402823466e38f, m1 = 3.402823466e38f, m2 = 3.402823466e38f;
        int j0 = 0, j1 = 0, j2 = 0;
#pragma unroll
        for (int s = 0; s < SPLITS; ++s) {    // ascending split = ascending index
#pragma unroll
            for (int u = 0; u < 3; ++u)
                top3_insert(sD[s][r][u], sI[s][r][u], m0, m1, m2, j0, j1, j2);
        }

        // one-hot "one" positions; zeros were laid down by the stream-ordered
        // hipMemsetAsync before this kernel launched.
        size_t sb = (size_t)row * 3 * 1024;
        out3f[sb + j0]        = 1.0f;
        out3f[sb + 1024 + j1] = 1.0f;
        out3f[sb + 2048 + j2] = 1.0f;

        const float4* e0q = (const float4*)(emb + (size_t)j0 * 64);
        const float4* e1q = (const float4*)(emb + (size_t)j1 * 64);
        const float4* e2q = (const float4*)(emb + (size_t)j2 * 64);
        v4f* o4 = (v4f*)(out0 + (size_t)row * 64);

        float lsum = 0.0f;
#pragma unroll
        for (int k4 = 0; k4 < 16; ++k4) {
            float4 a = e0q[k4], b = e1q[k4], c = e2q[k4];   // vectorized gathers
            float zx = zr[4 * k4], zy = zr[4 * k4 + 1];
            float zz = zr[4 * k4 + 2], zw = zr[4 * k4 + 3];
            v4f st;
            float zq, df;
            zq = ((a.x + b.x) + c.x) / 3.0f; df = zq - zx; st.x = zx + df; lsum = fmaf(df, df, lsum);
            zq = ((a.y + b.y) + c.y) / 3.0f; df = zq - zy; st.y = zy + df; lsum = fmaf(df, df, lsum);
            zq = ((a.z + b.z) + c.z) / 3.0f; df = zq - zz; st.z = zz + df; lsum = fmaf(df, df, lsum);
            zq = ((a.w + b.w) + c.w) / 3.0f; df = zq - zw; st.w = zw + df; lsum = fmaf(df, df, lsum);
            o4[k4] = st;                                    // plain store (no NT)
        }

        size_t ob = (size_t)row * 3;
        out4[ob]     = (float)j0;
        out4[ob + 1] = (float)j1;
        out4[ob + 2] = (float)j2;
        atomicAdd(&hist[j0], 1);
        atomicAdd(&hist[j1], 1);
        atomicAdd(&hist[j2], 1);

        // wave-level reduce of loss partial, one atomic per wave
#pragma unroll
        for (int off = 32; off >= 1; off >>= 1) lsum += __shfl_down(lsum, off);
        if ((t & 63) == 0) atomicAdd(lossAcc, lsum);
    }
}

// ---------------------------------------------------------------------------
// Perplexity from histogram + loss finalize (unchanged).
// ---------------------------------------------------------------------------
__global__ __launch_bounds__(256) void finalize_kernel(const int* __restrict__ hist,
                                                       const float* __restrict__ lossAcc,
                                                       float* __restrict__ out1,
                                                       float* __restrict__ out2) {
    __shared__ float red[256];
    int t = threadIdx.x;
    float local = 0.0f;
    for (int b = t; b < CB; b += 256) {
        float em = (float)hist[b] / 196608.0f;
        local += em * logf(em + 1e-10f);
    }
    red[t] = local;
    __syncthreads();
    for (int s = 128; s >= 1; s >>= 1) {
        if (t < s) red[t] += red[t + s];
        __syncthreads();
    }
    if (t == 0) {
        *out2 = expf(-red[0]);
        float m = *lossAcc / 4194304.0f;
        *out1 = 0.25f * m + m;     // BETA_C*mse + mse
    }
}

extern "C" void kernel_launch(void* const* d_in, const int* in_sizes, int n_in,
                              void* d_out, int out_size, void* d_ws, size_t ws_size,
                              hipStream_t stream) {
    const float* z   = (const float*)d_in[0];   // [16,64,64,64] -> 65536 x 64
    const float* emb = (const float*)d_in[1];   // [1024, 64]

    float* out  = (float*)d_out;
    float* out0 = out;                                    // z_q_st  4194304
    float* out1 = out + 4194304;                          // loss    1
    float* out2 = out + 4194305;                          // perplexity 1
    float* out3 = out + 4194306;                          // encodings 201326592
    float* out4 = out + 4194306 + 201326592ll;            // topk_idx (as float) 196608

    int*   hist    = (int*)d_ws;                          // 1024 ints @ 0
    float* lossAcc = (float*)((char*)d_ws + 4096);        // 1 float
    float* B       = (float*)((char*)d_ws + 8192);        // 1024 floats

    prep_kernel<<<4, 256, 0, stream>>>(emb, B, hist, lossAcc);
    // Zero the 805 MB encodings region via the runtime fill path (measured at
    // 6.27 TB/s on this very buffer each iteration, vs ~2.6 TB/s for any store
    // stream our kernels issue — rounds 2/3/4). Stream order guarantees the
    // zeros land before score_kernel scatters the ones.
    hipMemsetAsync(out3, 0, (size_t)N_ROWS * 3 * CB * sizeof(float), stream);
    score_kernel<<<N_ROWS / 64, 256, 0, stream>>>(z, emb, B, out0, out3, out4,
                                                  hist, lossAcc);
    finalize_kernel<<<1, 256, 0, stream>>>(hist, lossAcc, out1, out2);
}

// Round 6
// 1074.836 us; speedup vs baseline: 1.0163x; 1.0163x over previous
//
#include <hip/hip_runtime.h>
#include <math.h>

#define N_ROWS 65536
#define CB 1024
#define SPLITS 4
#define JS (CB / SPLITS)   // 256 codebook entries per split

typedef float v4f __attribute__((ext_vector_type(4)));

// ---------------------------------------------------------------------------
// Exact emulation of numpy's pairwise_sum for n=64 fp32 (AVX-512 path).
// fp contract OFF so the squares are not fused into the adds.
// ---------------------------------------------------------------------------
__device__ __forceinline__ float tree_sum64_sq(const float* x) {
#pragma clang fp contract(off)
    float sq[64];
#pragma unroll
    for (int i = 0; i < 64; ++i) sq[i] = x[i] * x[i];
    float s[16];
#pragma unroll
    for (int l = 0; l < 16; ++l) s[l] = (sq[l] + sq[l + 16]) + (sq[l + 32] + sq[l + 48]);
    float t[8];
#pragma unroll
    for (int l = 0; l < 8; ++l) t[l] = s[l] + s[l + 8];
    float u[4];
#pragma unroll
    for (int l = 0; l < 4; ++l) u[l] = t[l] + t[l + 4];
    float v0 = u[0] + u[2];
    float v1 = u[1] + u[3];
    return v0 + v1;
}

// sorted-triple insert, strict < (ties keep earlier-inserted = lower index,
// matching jax.lax.top_k stable tie-breaking when fed in ascending index order)
__device__ __forceinline__ void top3_insert(float d, int j,
                                            float& v0, float& v1, float& v2,
                                            int& i0, int& i1, int& i2) {
    bool b0 = d < v0, b1 = d < v1, b2 = d < v2;
    v2 = b1 ? v1 : (b2 ? d : v2);
    i2 = b1 ? i1 : (b2 ? j : i2);
    v1 = b0 ? v0 : (b1 ? d : v1);
    i1 = b0 ? i0 : (b1 ? j : i1);
    v0 = b0 ? d : v0;
    i0 = b0 ? j : i0;
}

// ---------------------------------------------------------------------------
// B[j] = np.sum(emb[j]**2) (exact tree emulation) + zero hist/lossAcc.
// ---------------------------------------------------------------------------
__global__ __launch_bounds__(256) void prep_kernel(const float* __restrict__ emb,
                                                   float* __restrict__ B,
                                                   int* __restrict__ hist,
                                                   float* __restrict__ lossAcc) {
    int j = blockIdx.x * 256 + threadIdx.x;
    if (j >= CB) return;
    float e[64];
    const float4* e4 = (const float4*)(emb + (size_t)j * 64);
#pragma unroll
    for (int k = 0; k < 16; ++k) {
        float4 v = e4[k];
        e[4 * k] = v.x; e[4 * k + 1] = v.y; e[4 * k + 2] = v.z; e[4 * k + 3] = v.w;
    }
    B[j] = tree_sum64_sq(e);
    hist[j] = 0;
    if (j == 0) *lossAcc = 0.0f;
}

// ---------------------------------------------------------------------------
// A/B probe arm B: dedicated zero-fill kernel. Plain (non-NT) stores,
// 16B-aligned base, consecutive lanes -> consecutive 16B (full 64B lines per
// wave), grid-stride, fill-kernel-shaped (tiny VGPR footprint, no reads).
// Tests whether a kernel-issued aligned non-NT store stream reaches the
// 6.2 TB/s the runtime's fillBufferAligned demonstrates, or caps at the
// ~2.6 TB/s every previous (confounded) arrangement measured.
// ---------------------------------------------------------------------------
#define ZF_GRID 2048
__global__ __launch_bounds__(256) void zerofill_kernel(v4f* __restrict__ p, int n4) {
    v4f z = {0.0f, 0.0f, 0.0f, 0.0f};
    int stride = ZF_GRID * 256;
    for (int m = blockIdx.x * 256 + threadIdx.x; m < n4; m += stride)
        p[m] = z;
}

// ---------------------------------------------------------------------------
// Score + merge + epilogue + one-hot ONES (unchanged from R5, known-good).
//  * `split` through readfirstlane -> emb/B loads provably uniform -> scalar
//    s_load path (losing this was 4x, round 1).
//  * Zeros for out3 are laid down by the stream-ordered fills before this
//    kernel; only the <=192 "one" positions per block are scattered here.
// Scoring FP order, merge tie semantics, epilogue: bit-identical throughout.
// ---------------------------------------------------------------------------
__global__ __launch_bounds__(256) void score_kernel(const float* __restrict__ z,
                                                    const float* __restrict__ emb,
                                                    const float* __restrict__ B,
                                                    float* __restrict__ out0,
                                                    float* __restrict__ out3f,
                                                    float* __restrict__ out4,
                                                    int* __restrict__ hist,
                                                    float* __restrict__ lossAcc) {
    __shared__ float sD[SPLITS][64][3];
    __shared__ int   sI[SPLITS][64][3];

    int t = threadIdx.x;
    int r = t & 63;
    int split = __builtin_amdgcn_readfirstlane(t >> 6);   // uniform -> scalar loads
    int row = blockIdx.x * 64 + r;

    float zr[64];
    const float4* z4 = (const float4*)(z + (size_t)row * 64);
#pragma unroll
    for (int k = 0; k < 16; ++k) {
        float4 v = z4[k];
        zr[4 * k] = v.x; zr[4 * k + 1] = v.y; zr[4 * k + 2] = v.z; zr[4 * k + 3] = v.w;
    }
    float A = tree_sum64_sq(zr);

    float v0 = 3.402823466e38f, v1 = 3.402823466e38f, v2 = 3.402823466e38f;
    int i0 = 0, i1 = 0, i2 = 0;
    int jbase = split * JS;

#pragma unroll 2
    for (int jj = 0; jj < JS; ++jj) {
        int j = jbase + jj;                   // uniform (split is readfirstlane'd)
        const float4* e4 = (const float4*)(emb + (size_t)j * 64);
        float Bj = B[j];                      // uniform -> scalar load
        float acc = 0.0f;
#pragma unroll
        for (int k = 0; k < 16; ++k) {
            float4 e = e4[k];                 // uniform -> scalar loads
            acc = fmaf(zr[4 * k],     e.x, acc);
            acc = fmaf(zr[4 * k + 1], e.y, acc);
            acc = fmaf(zr[4 * k + 2], e.z, acc);
            acc = fmaf(zr[4 * k + 3], e.w, acc);
        }
        float d = (A + Bj) - 2.0f * acc;      // fma-contraction bit-identical
        top3_insert(d, j, v0, v1, v2, i0, i1, i2);
    }

    sD[split][r][0] = v0; sD[split][r][1] = v1; sD[split][r][2] = v2;
    sI[split][r][0] = i0; sI[split][r][1] = i1; sI[split][r][2] = i2;
    __syncthreads();

    if (t < 64) {                             // wave 0: zr holds row's z (split 0)
        float m0 = 3.402823466e38f, m1 = 3.402823466e38f, m2 = 3.402823466e38f;
        int j0 = 0, j1 = 0, j2 = 0;
#pragma unroll
        for (int s = 0; s < SPLITS; ++s) {    // ascending split = ascending index
#pragma unroll
            for (int u = 0; u < 3; ++u)
                top3_insert(sD[s][r][u], sI[s][r][u], m0, m1, m2, j0, j1, j2);
        }

        // one-hot "one" positions; zeros already durable (stream order)
        size_t sb = (size_t)row * 3 * 1024;
        out3f[sb + j0]        = 1.0f;
        out3f[sb + 1024 + j1] = 1.0f;
        out3f[sb + 2048 + j2] = 1.0f;

        const float4* e0q = (const float4*)(emb + (size_t)j0 * 64);
        const float4* e1q = (const float4*)(emb + (size_t)j1 * 64);
        const float4* e2q = (const float4*)(emb + (size_t)j2 * 64);
        v4f* o4 = (v4f*)(out0 + (size_t)row * 64);

        float lsum = 0.0f;
#pragma unroll
        for (int k4 = 0; k4 < 16; ++k4) {
            float4 a = e0q[k4], b = e1q[k4], c = e2q[k4];   // vectorized gathers
            float zx = zr[4 * k4], zy = zr[4 * k4 + 1];
            float zz = zr[4 * k4 + 2], zw = zr[4 * k4 + 3];
            v4f st;
            float zq, df;
            zq = ((a.x + b.x) + c.x) / 3.0f; df = zq - zx; st.x = zx + df; lsum = fmaf(df, df, lsum);
            zq = ((a.y + b.y) + c.y) / 3.0f; df = zq - zy; st.y = zy + df; lsum = fmaf(df, df, lsum);
            zq = ((a.z + b.z) + c.z) / 3.0f; df = zq - zz; st.z = zz + df; lsum = fmaf(df, df, lsum);
            zq = ((a.w + b.w) + c.w) / 3.0f; df = zq - zw; st.w = zw + df; lsum = fmaf(df, df, lsum);
            o4[k4] = st;                                    // plain store (no NT)
        }

        size_t ob = (size_t)row * 3;
        out4[ob]     = (float)j0;
        out4[ob + 1] = (float)j1;
        out4[ob + 2] = (float)j2;
        atomicAdd(&hist[j0], 1);
        atomicAdd(&hist[j1], 1);
        atomicAdd(&hist[j2], 1);

        // wave-level reduce of loss partial, one atomic per wave
#pragma unroll
        for (int off = 32; off >= 1; off >>= 1) lsum += __shfl_down(lsum, off);
        if ((t & 63) == 0) atomicAdd(lossAcc, lsum);
    }
}

// ---------------------------------------------------------------------------
// Perplexity from histogram + loss finalize (unchanged).
// ---------------------------------------------------------------------------
__global__ __launch_bounds__(256) void finalize_kernel(const int* __restrict__ hist,
                                                       const float* __restrict__ lossAcc,
                                                       float* __restrict__ out1,
                                                       float* __restrict__ out2) {
    __shared__ float red[256];
    int t = threadIdx.x;
    float local = 0.0f;
    for (int b = t; b < CB; b += 256) {
        float em = (float)hist[b] / 196608.0f;
        local += em * logf(em + 1e-10f);
    }
    red[t] = local;
    __syncthreads();
    for (int s = 128; s >= 1; s >>= 1) {
        if (t < s) red[t] += red[t + s];
        __syncthreads();
    }
    if (t == 0) {
        *out2 = expf(-red[0]);
        float m = *lossAcc / 4194304.0f;
        *out1 = 0.25f * m + m;     // BETA_C*mse + mse
    }
}

extern "C" void kernel_launch(void* const* d_in, const int* in_sizes, int n_in,
                              void* d_out, int out_size, void* d_ws, size_t ws_size,
                              hipStream_t stream) {
    const float* z   = (const float*)d_in[0];   // [16,64,64,64] -> 65536 x 64
    const float* emb = (const float*)d_in[1];   // [1024, 64]

    float* out  = (float*)d_out;
    float* out0 = out;                                    // z_q_st  4194304
    float* out1 = out + 4194304;                          // loss    1
    float* out2 = out + 4194305;                          // perplexity 1
    float* out3 = out + 4194306;                          // encodings 201326592
    float* out4 = out + 4194306 + 201326592ll;            // topk_idx (as float) 196608

    int*   hist    = (int*)d_ws;                          // 1024 ints @ 0
    float* lossAcc = (float*)((char*)d_ws + 4096);        // 1 float
    float* B       = (float*)((char*)d_ws + 8192);        // 1024 floats

    prep_kernel<<<4, 256, 0, stream>>>(emb, B, hist, lossAcc);

    // ---- A/B probe on the 805 MB zero fill --------------------------------
    // The zeroed range is EXTENDED to the 16B-aligned range
    // [float 4194304, buffer end): additionally covers only out1/out2
    // (rewritten by finalize) and out4 (fully rewritten by score_kernel),
    // so correctness is unaffected by the over-zeroing.
    //
    // Arm A: runtime memset from the PERFECTLY ALIGNED base (byte 2^24).
    //   R5's memset used the 8-mod-16 out3 pointer and (by budget arithmetic)
    //   ran at ~2.6 TB/s — this tests whether base alignment selects the
    //   6.2 TB/s fillBufferAligned path.
    //   Covers floats [4194304, 104857600): 384 MiB.
    hipMemsetAsync(out + 4194304, 0, 402653184ull, stream);

    // Arm B: our own plain-store aligned fill kernel.
    //   Covers float4s [26214400, 51429376) = floats [104857600, 205717504):
    //   ~385 MiB, ending 2 floats short of buffer end (those 2 are out4
    //   entries rewritten by score_kernel anyway).
    zerofill_kernel<<<ZF_GRID, 256, 0, stream>>>((v4f*)(out + 104857600), 25214976);

    score_kernel<<<N_ROWS / 64, 256, 0, stream>>>(z, emb, B, out0, out3, out4,
                                                  hist, lossAcc);
    finalize_kernel<<<1, 256, 0, stream>>>(hist, lossAcc, out1, out2);
}